// Round 1
// baseline (11506.913 us; speedup 1.0000x reference)
//
#include <hip/hip_runtime.h>
#include <stdint.h>

typedef __attribute__((ext_vector_type(8))) short short8;
typedef __attribute__((ext_vector_type(4))) float f32x4;

#define ROWS 64
#define LDH  168      // bf16 elems per h-row in LDS: 128 h + 6 x + 1 bias col (134) + pad
#define NTT  15
#define NIN  6

// packed weight sets (shorts): set0 (L0, 5 frags per (jt,g)) @0, size 81920
// set1 (L1, 9 frags) @81920 size 147456 ; set2 (dec) @229376 size 147456
#define PK0_OFF 0
#define PK1_OFF 81920
#define PK2_OFF 229376
#define PK_TOTAL 376832
#define DBASE_BYTE_OFF 753664   // PK_TOTAL*2

__device__ __forceinline__ unsigned short f2bf(float f){
  unsigned int u = __builtin_bit_cast(unsigned int, f);
  u += 0x7fffu + ((u >> 16) & 1u);
  return (unsigned short)(u >> 16);
}
__device__ __forceinline__ float sigf(float x){
  return __builtin_amdgcn_rcpf(1.0f + __expf(-x));
}
__device__ __forceinline__ float tanhf_(float x){
  return 1.0f - 2.0f*__builtin_amdgcn_rcpf(1.0f + __expf(2.0f*x));
}

// ---------------- prep: pack weights to bf16 MFMA fragments ----------------
// B-frag for (n,k): lane holds n = nt*16+(lane&15), k = kt*32+(lane>>4)*8+j.
// Extended-K (160) sets fold x-input weights (k=128..133) and bias (k=134).
__global__ void pack_w(const float* __restrict__ Wih0, const float* __restrict__ Whh0,
                       const float* __restrict__ b0,
                       const float* __restrict__ Wih1, const float* __restrict__ Whh1,
                       const float* __restrict__ b1,
                       const float* __restrict__ Wihd, const float* __restrict__ Whhd,
                       const float* __restrict__ bd,
                       unsigned short* __restrict__ pk)
{
  int idx = blockIdx.x*256 + threadIdx.x;
  if (idx >= PK_TOTAL) return;
  int set, e;
  if (idx < PK1_OFF)      { set = 0; e = idx; }
  else if (idx < PK2_OFF) { set = 1; e = idx - PK1_OFF; }
  else                    { set = 2; e = idx - PK2_OFF; }
  int j    = e & 7;
  int lane = (e >> 3) & 63;
  int rest = e >> 9;
  int nf   = (set == 0) ? 5 : 9;
  int f    = rest % nf;
  int gj   = rest / nf;
  int g    = gj & 3, jt = gj >> 2;
  int n    = g*128 + jt*16 + (lane & 15);
  int kk   = (lane >> 4)*8 + j;          // 0..31 within a k-tile
  float v = 0.f;
  if (set == 0){
    if (f < 4) v = Whh0[n*128 + f*32 + kk];
    else {                               // extension tile: x weights + bias
      if (kk < 6)       v = Wih0[n*6 + kk];
      else if (kk == 6) v = b0[n];       // k = 134
    }
  } else {
    const float* Wi = (set==1) ? Wih1 : Wihd;
    const float* Wh = (set==1) ? Whh1 : Whhd;
    const float* bb = (set==1) ? b1   : bd;
    if (f < 4) v = Wi[n*128 + f*32 + kk];
    else {
      int k2 = (f-4)*32 + kk;            // 0..159
      if (k2 < 128)      v = Wh[n*128 + k2];
      else if (k2 == 134) v = bb[n];
    }
  }
  pk[idx] = f2bf(v);
}

// dec_base[s][j] = bp[j] + sum_k emb[s][k]*Wp[j][3+k]
__global__ void prep_decbase(const float* __restrict__ emb, const float* __restrict__ Wp,
                             const float* __restrict__ bp, float* __restrict__ dbase)
{
  int idx = blockIdx.x*128 + threadIdx.x;
  if (idx >= 1280) return;
  int s = idx >> 7, j = idx & 127;
  float acc = bp[j];
  for (int k = 0; k < 128; ++k) acc += emb[s*128 + k] * Wp[j*131 + 3 + k];
  dbase[idx] = acc;
}

// ---------------- main fused kernel ----------------
__global__ __launch_bounds__(256, 2)
void traj_main(const float* __restrict__ x,
               const unsigned short* __restrict__ pk,
               const float* __restrict__ dbase,
               const float* __restrict__ Wp,
               const float* __restrict__ Wm, const float* __restrict__ bm,
               const float* __restrict__ Wsd, const float* __restrict__ bsd,
               const float* __restrict__ lng, const float* __restrict__ lnb,
               float* __restrict__ out)
{
  __shared__ __align__(16) unsigned short hA[ROWS*LDH];  // h0 / dec_in (+x, +1 col)
  __shared__ __align__(16) unsigned short hB[ROWS*LDH];  // h1 / dec h  (+1 col)

  const int tid  = threadIdx.x;
  const int wave = tid >> 6;
  const int lane = tid & 63;
  const int lidx = lane & 15;
  const int lgrp = lane >> 4;
  const int wrow0 = wave * 16;       // wave's 16-row block within the WG tile
  const int lrow  = wrow0 + lgrp*4;  // wave-local row of acc reg 0
  const int row0  = blockIdx.x * ROWS;

  const unsigned short* pk0 = pk + PK0_OFF;
  const unsigned short* pk1 = pk + PK1_OFF;
  const unsigned short* pk2 = pk + PK2_OFF;

  // init LDS: zeros, bias column (134) = 1.0 bf16
  for (int i = tid; i < ROWS*LDH; i += 256){
    unsigned short v = ((i % LDH) == 134) ? (unsigned short)0x3F80 : (unsigned short)0;
    hA[i] = v; hB[i] = v;
  }

  float c0[4][8], c1[4][8];
  #pragma unroll
  for (int r = 0; r < 4; ++r)
    #pragma unroll
    for (int q = 0; q < 8; ++q){ c0[r][q] = 0.f; c1[r][q] = 0.f; }

  __syncthreads();

  const int arow = (wrow0 + lidx)*LDH + lgrp*8;   // A-frag base (this wave, row lidx)

  // ===================== encoder =====================
  #pragma unroll 1
  for (int t = 0; t < NTT; ++t){
    // stage x_t as bf16 into hA cols 128..133
    for (int i = tid; i < ROWS*NIN; i += 256){
      int r = i / NIN, k = i - r*NIN;
      hA[r*LDH + 128 + k] = f2bf(x[(size_t)(row0 + r)*(NTT*NIN) + t*NIN + k]);
    }
    __syncthreads();

    // ---- layer 0: g = [h0, x_t, 1] @ [Whh0|Wih0|b0]^T  (K=160) ----
    short8 a0[5];
    #pragma unroll
    for (int kt = 0; kt < 5; ++kt) a0[kt] = *(const short8*)&hA[arow + kt*32];
    #pragma unroll
    for (int jt = 0; jt < 8; ++jt){
      const int col = jt*16 + lidx;
      f32x4 acc[4];
      #pragma unroll
      for (int g = 0; g < 4; ++g){
        f32x4 a = {0.f, 0.f, 0.f, 0.f};
        #pragma unroll
        for (int kt = 0; kt < 5; ++kt){
          short8 b = *(const short8*)&pk0[(size_t)(((jt*4+g)*5 + kt)*512) + lane*8];
          a = __builtin_amdgcn_mfma_f32_16x16x32_bf16(a0[kt], b, a, 0, 0, 0);
        }
        acc[g] = a;
      }
      #pragma unroll
      for (int r = 0; r < 4; ++r){
        float iv = sigf(acc[0][r]);
        float fv = sigf(acc[1][r]);
        float gv = tanhf_(acc[2][r]);
        float ov = sigf(acc[3][r]);
        float c  = fv*c0[r][jt] + iv*gv;
        c0[r][jt] = c;
        hA[(lrow + r)*LDH + col] = f2bf(ov*tanhf_(c));
      }
    }
    __syncthreads();

    // ---- layer 1: g = h0_new@Wih1^T + [h1,1]@[Whh1|b1]^T ----
    short8 aI[4], aH[5];
    #pragma unroll
    for (int kt = 0; kt < 4; ++kt) aI[kt] = *(const short8*)&hA[arow + kt*32];
    #pragma unroll
    for (int kt = 0; kt < 5; ++kt) aH[kt] = *(const short8*)&hB[arow + kt*32];
    #pragma unroll
    for (int jt = 0; jt < 8; ++jt){
      const int col = jt*16 + lidx;
      f32x4 acc[4];
      #pragma unroll
      for (int g = 0; g < 4; ++g){
        f32x4 a = {0.f, 0.f, 0.f, 0.f};
        const size_t base = (size_t)((jt*4+g)*9)*512 + lane*8;
        #pragma unroll
        for (int kt = 0; kt < 4; ++kt){
          short8 b = *(const short8*)&pk1[base + kt*512];
          a = __builtin_amdgcn_mfma_f32_16x16x32_bf16(aI[kt], b, a, 0, 0, 0);
        }
        #pragma unroll
        for (int kt = 0; kt < 5; ++kt){
          short8 b = *(const short8*)&pk1[base + (4+kt)*512];
          a = __builtin_amdgcn_mfma_f32_16x16x32_bf16(aH[kt], b, a, 0, 0, 0);
        }
        acc[g] = a;
      }
      #pragma unroll
      for (int r = 0; r < 4; ++r){
        float iv = sigf(acc[0][r]);
        float fv = sigf(acc[1][r]);
        float gv = tanhf_(acc[2][r]);
        float ov = sigf(acc[3][r]);
        float c  = fv*c1[r][jt] + iv*gv;
        c1[r][jt] = c;
        hB[(lrow + r)*LDH + col] = f2bf(ov*tanhf_(c));
      }
    }
    __syncthreads();
  }

  // ===================== decoder =====================
  float prev[4][3];
  #pragma unroll
  for (int r = 0; r < 4; ++r)
    #pragma unroll
    for (int k = 0; k < 3; ++k)
      prev[r][k] = x[(size_t)(row0 + lrow + r)*(NTT*NIN) + 14*NIN + k];

  #pragma unroll 1
  for (int s = 0; s < 10; ++s){
    // dec_in = relu(dbase + prev @ Wp[:, :3]^T) -> hA cols 0..127
    #pragma unroll
    for (int jt = 0; jt < 8; ++jt){
      const int col = jt*16 + lidx;
      float base = dbase[s*128 + col];
      float w0 = Wp[col*131 + 0], w1 = Wp[col*131 + 1], w2 = Wp[col*131 + 2];
      #pragma unroll
      for (int r = 0; r < 4; ++r){
        float v = base + prev[r][0]*w0 + prev[r][1]*w1 + prev[r][2]*w2;
        hA[(lrow + r)*LDH + col] = f2bf(v > 0.f ? v : 0.f);
      }
    }
    __syncthreads();

    short8 aI[4], aH[5];
    #pragma unroll
    for (int kt = 0; kt < 4; ++kt) aI[kt] = *(const short8*)&hA[arow + kt*32];
    #pragma unroll
    for (int kt = 0; kt < 5; ++kt) aH[kt] = *(const short8*)&hB[arow + kt*32];
    float hn[4][8];
    #pragma unroll
    for (int jt = 0; jt < 8; ++jt){
      const int col = jt*16 + lidx;
      f32x4 acc[4];
      #pragma unroll
      for (int g = 0; g < 4; ++g){
        f32x4 a = {0.f, 0.f, 0.f, 0.f};
        const size_t base = (size_t)((jt*4+g)*9)*512 + lane*8;
        #pragma unroll
        for (int kt = 0; kt < 4; ++kt){
          short8 b = *(const short8*)&pk2[base + kt*512];
          a = __builtin_amdgcn_mfma_f32_16x16x32_bf16(aI[kt], b, a, 0, 0, 0);
        }
        #pragma unroll
        for (int kt = 0; kt < 5; ++kt){
          short8 b = *(const short8*)&pk2[base + (4+kt)*512];
          a = __builtin_amdgcn_mfma_f32_16x16x32_bf16(aH[kt], b, a, 0, 0, 0);
        }
        acc[g] = a;
      }
      #pragma unroll
      for (int r = 0; r < 4; ++r){
        float iv = sigf(acc[0][r]);
        float fv = sigf(acc[1][r]);
        float gv = tanhf_(acc[2][r]);
        float ov = sigf(acc[3][r]);
        float c  = fv*c1[r][jt] + iv*gv;
        c1[r][jt] = c;
        float h = ov*tanhf_(c);
        hn[r][jt] = h;
        hB[(lrow + r)*LDH + col] = f2bf(h);
      }
    }

    // LayerNorm (register + shfl over the 16 lanes sharing lane>>4)
    float mu_[4], rs_[4];
    #pragma unroll
    for (int r = 0; r < 4; ++r){
      float sm = 0.f;
      #pragma unroll
      for (int q = 0; q < 8; ++q) sm += hn[r][q];
      sm += __shfl_xor(sm, 1); sm += __shfl_xor(sm, 2);
      sm += __shfl_xor(sm, 4); sm += __shfl_xor(sm, 8);
      float mu = sm * (1.f/128.f);
      float vs = 0.f;
      #pragma unroll
      for (int q = 0; q < 8; ++q){ float d = hn[r][q] - mu; vs += d*d; }
      vs += __shfl_xor(vs, 1); vs += __shfl_xor(vs, 2);
      vs += __shfl_xor(vs, 4); vs += __shfl_xor(vs, 8);
      mu_[r] = mu;
      rs_[r] = __builtin_amdgcn_rsqf(vs*(1.f/128.f) + 1e-5f);
    }
    float pm[4][3], ps[4][3];
    #pragma unroll
    for (int r = 0; r < 4; ++r)
      #pragma unroll
      for (int o = 0; o < 3; ++o){ pm[r][o] = 0.f; ps[r][o] = 0.f; }
    #pragma unroll
    for (int jt = 0; jt < 8; ++jt){
      const int col = jt*16 + lidx;
      float gg = lng[col], bb = lnb[col];
      float wm0 = Wm[col], wm1 = Wm[128+col], wm2 = Wm[256+col];
      float ws0 = Wsd[col], ws1 = Wsd[128+col], ws2 = Wsd[256+col];
      #pragma unroll
      for (int r = 0; r < 4; ++r){
        float f = (hn[r][jt] - mu_[r])*rs_[r]*gg + bb;
        pm[r][0] += f*wm0; pm[r][1] += f*wm1; pm[r][2] += f*wm2;
        ps[r][0] += f*ws0; ps[r][1] += f*ws1; ps[r][2] += f*ws2;
      }
    }
    #pragma unroll
    for (int r = 0; r < 4; ++r){
      #pragma unroll
      for (int o = 0; o < 3; ++o){
        float v = pm[r][o];
        v += __shfl_xor(v, 1); v += __shfl_xor(v, 2);
        v += __shfl_xor(v, 4); v += __shfl_xor(v, 8);
        v += bm[o];
        float u = ps[r][o];
        u += __shfl_xor(u, 1); u += __shfl_xor(u, 2);
        u += __shfl_xor(u, 4); u += __shfl_xor(u, 8);
        u += bsd[o];
        u = fminf(fmaxf(u, -6.f), 3.f);
        prev[r][o] = v;
        if (lidx == 0){
          size_t ro = (size_t)(row0 + lrow + r)*30 + (size_t)s*3 + o;
          out[ro] = v;                        // means
          out[(size_t)65536*30 + ro] = u;     // log_stds
        }
      }
    }
    __syncthreads();
  }
}

extern "C" void kernel_launch(void* const* d_in, const int* in_sizes, int n_in,
                              void* d_out, int out_size, void* d_ws, size_t ws_size,
                              hipStream_t stream)
{
  const float* x    = (const float*)d_in[0];
  const float* Wih0 = (const float*)d_in[1];
  const float* Whh0 = (const float*)d_in[2];
  const float* b0   = (const float*)d_in[3];
  const float* Wih1 = (const float*)d_in[4];
  const float* Whh1 = (const float*)d_in[5];
  const float* b1   = (const float*)d_in[6];
  const float* Wihd = (const float*)d_in[7];
  const float* Whhd = (const float*)d_in[8];
  const float* bd   = (const float*)d_in[9];
  const float* emb  = (const float*)d_in[10];
  const float* Wp   = (const float*)d_in[11];
  const float* bp   = (const float*)d_in[12];
  const float* Wm   = (const float*)d_in[13];
  const float* bm   = (const float*)d_in[14];
  const float* Wsd  = (const float*)d_in[15];
  const float* bsd  = (const float*)d_in[16];
  const float* lng  = (const float*)d_in[17];
  const float* lnb  = (const float*)d_in[18];

  unsigned short* pk = (unsigned short*)d_ws;
  float* dbase = (float*)((char*)d_ws + DBASE_BYTE_OFF);

  pack_w<<<(PK_TOTAL + 255)/256, 256, 0, stream>>>(Wih0, Whh0, b0, Wih1, Whh1, b1,
                                                   Wihd, Whhd, bd, pk);
  prep_decbase<<<10, 128, 0, stream>>>(emb, Wp, bp, dbase);
  traj_main<<<65536/ROWS, 256, 0, stream>>>(x, pk, dbase, Wp, Wm, bm, Wsd, bsd,
                                            lng, lnb, (float*)d_out);
}

// Round 2
// 2163.300 us; speedup vs baseline: 5.3191x; 5.3191x over previous
//
#include <hip/hip_runtime.h>
#include <stdint.h>

typedef __attribute__((ext_vector_type(8))) short short8;
typedef __attribute__((ext_vector_type(4))) float f32x4;

#define NT 15

// packed bf16 weight fragments in d_ws (element offsets, shorts)
#define SET0 0          // L0: 32 (jt,g) pairs x 5 kt x 512
#define SET1 81920      // L1: 32 pairs x 8 kt x 512
#define SET2 212992     // dec: same shape as L1
#define SET3 344064     // heads [Wm;Ws]: 4 kt x 512
#define PK_TOTAL 346112
#define DBASE_OFF (PK_TOTAL*2)   // byte offset of dbase in ws

__device__ __forceinline__ unsigned short f2bf(float f){
  unsigned int u = __builtin_bit_cast(unsigned int, f);
  u += 0x7fffu + ((u >> 16) & 1u);
  return (unsigned short)(u >> 16);
}
__device__ __forceinline__ float sigf(float x){
  return __builtin_amdgcn_rcpf(1.0f + __expf(-x));
}
__device__ __forceinline__ float tanhf_(float x){
  return 1.0f - 2.0f*__builtin_amdgcn_rcpf(1.0f + __expf(2.0f*x));
}
// XOR-swizzled LDS index (shorts): spreads stride-256B rows across banks.
// Applies uniformly to b16 writes and 16B-granule b128 reads (flips bits 3..5).
__device__ __forceinline__ int sidx(int row, int col){
  return row*128 + (col ^ ((row & 7) << 3));
}

// ---------------- prep: pack weights to bf16 MFMA fragments ----------------
// Fragment (n,k): lane holds n = 16-col tile + (lane&15), k = kt*32+(lane>>4)*8+j.
__global__ void pack_w(const float* __restrict__ Wih0, const float* __restrict__ Whh0,
                       const float* __restrict__ Wih1, const float* __restrict__ Whh1,
                       const float* __restrict__ Wihd, const float* __restrict__ Whhd,
                       const float* __restrict__ Wm,  const float* __restrict__ Ws,
                       unsigned short* __restrict__ pk)
{
  int idx = blockIdx.x*256 + threadIdx.x;
  if (idx >= PK_TOTAL) return;
  float v = 0.f;
  if (idx >= SET3){
    int e = idx - SET3;
    int j = e & 7, lane = (e >> 3) & 63, kt = e >> 9;
    int n = lane & 15;
    int k = kt*32 + (lane >> 4)*8 + j;
    if (n < 3) v = Wm[n*128 + k];
    else if (n < 6) v = Ws[(n-3)*128 + k];
  } else {
    int set, e;
    if (idx < SET1){ set = 0; e = idx; }
    else if (idx < SET2){ set = 1; e = idx - SET1; }
    else { set = 2; e = idx - SET2; }
    int j = e & 7, lane = (e >> 3) & 63, rest = e >> 9;
    int nf = (set == 0) ? 5 : 8;
    int kt = rest % nf, pair = rest / nf;
    int g = pair & 3, jt = pair >> 2;
    int n = g*128 + jt*16 + (lane & 15);
    int kk = (lane >> 4)*8 + j;
    if (set == 0){
      if (kt < 4) v = Whh0[n*128 + kt*32 + kk];          // K 0..127 = h0
      else if (kk < 6) v = Wih0[n*6 + kk];               // K-ext tile = x
    } else {
      const float* Wi = (set == 1) ? Wih1 : Wihd;
      const float* Wh = (set == 1) ? Whh1 : Whhd;
      v = (kt < 4) ? Wi[n*128 + kt*32 + kk] : Wh[n*128 + (kt-4)*32 + kk];
    }
  }
  pk[idx] = f2bf(v);
}

// dec_base[s][j] = bp[j] + sum_k emb[s][k]*Wp[j][3+k]
__global__ void prep_decbase(const float* __restrict__ emb, const float* __restrict__ Wp,
                             const float* __restrict__ bp, float* __restrict__ dbase)
{
  int idx = blockIdx.x*128 + threadIdx.x;
  if (idx >= 1280) return;
  int s = idx >> 7, j = idx & 127;
  float acc = bp[j];
  for (int k = 0; k < 128; ++k) acc += emb[s*128 + k] * Wp[j*131 + 3 + k];
  dbase[idx] = acc;
}

union DecShared {
  unsigned short xs[NT*64*8];                 // encoder: x staged bf16 [t][row][8]
  struct {
    float sred[8][64][2];                     // LN partials per wave
    float mus[64][2];                         // mu, rstd per row
    float prevb[64][4];                       // prev-mu broadcast
  } d;
};

// ---------------- main fused kernel ----------------
// 512 thr = 8 waves; block owns 64 rows; wave w owns gate-columns [w*16,w*16+16)
// (all 4 gates). L0/L1 weights streamed once/step from L2; dec weights persistent.
__global__ __launch_bounds__(512)
void traj_main(const float* __restrict__ x,
               const unsigned short* __restrict__ pk,
               const float* __restrict__ dbase,
               const float* __restrict__ b0g, const float* __restrict__ b1g,
               const float* __restrict__ bdg,
               const float* __restrict__ Wp,
               const float* __restrict__ bm, const float* __restrict__ bs,
               const float* __restrict__ lng, const float* __restrict__ lnb,
               float* __restrict__ out)
{
  __shared__ __align__(16) unsigned short hA[2][64*128];
  __shared__ __align__(16) unsigned short hB[2][64*128];
  __shared__ __align__(16) DecShared u;

  const int tid  = threadIdx.x;
  const int w    = tid >> 6;
  const int lane = tid & 63;
  const int lidx = lane & 15;
  const int lgrp = lane >> 4;
  const int col  = w*16 + lidx;
  const int row0 = blockIdx.x * 64;

  for (int i = tid; i < 64*128; i += 512){ hA[0][i] = 0; hB[0][i] = 0; }
  for (int i = tid; i < NT*64*8; i += 512){
    int k8 = i & 7, r = (i >> 3) & 63, t = i >> 9;
    u.xs[i] = (k8 < 6) ? f2bf(x[(size_t)(row0 + r)*90 + t*6 + k8]) : (unsigned short)0;
  }

  float b0v[4], b1v[4];
  #pragma unroll
  for (int g = 0; g < 4; ++g){ b0v[g] = b0g[g*128 + col]; b1v[g] = b1g[g*128 + col]; }

  float c0[4][4], c1[4][4];
  #pragma unroll
  for (int m = 0; m < 4; ++m)
    #pragma unroll
    for (int r = 0; r < 4; ++r){ c0[m][r] = 0.f; c1[m][r] = 0.f; }

  __syncthreads();

  const unsigned short* pw0 = pk + SET0 + (w*4)*(5*512) + lane*8;
  const unsigned short* pw1 = pk + SET1 + (w*4)*(8*512) + lane*8;

  int ca = 0, cb = 0;
  #pragma unroll 1
  for (int t = 0; t < NT; ++t){
    // ---------- layer 0: [h0 | x_t] @ W^T ----------
    short8 w0f[4][5];
    #pragma unroll
    for (int g = 0; g < 4; ++g)
      #pragma unroll
      for (int kt = 0; kt < 5; ++kt)
        w0f[g][kt] = *(const short8*)&pw0[(g*5 + kt)*512];
    #pragma unroll
    for (int m = 0; m < 4; ++m){
      const int arow = m*16 + lidx;
      short8 a[5];
      #pragma unroll
      for (int kt = 0; kt < 4; ++kt)
        a[kt] = *(const short8*)&hA[ca][sidx(arow, kt*32 + lgrp*8)];
      short8 ax = {0,0,0,0,0,0,0,0};
      if (lgrp == 0) ax = *(const short8*)&u.xs[(t*64 + arow)*8];
      a[4] = ax;
      f32x4 acc[4];
      #pragma unroll
      for (int g = 0; g < 4; ++g){
        f32x4 s = {0.f,0.f,0.f,0.f};
        #pragma unroll
        for (int kt = 0; kt < 5; ++kt)
          s = __builtin_amdgcn_mfma_f32_16x16x32_bf16(a[kt], w0f[g][kt], s, 0, 0, 0);
        acc[g] = s;
      }
      #pragma unroll
      for (int r = 0; r < 4; ++r){
        float iv = sigf(acc[0][r] + b0v[0]);
        float fv = sigf(acc[1][r] + b0v[1]);
        float gv = tanhf_(acc[2][r] + b0v[2]);
        float ov = sigf(acc[3][r] + b0v[3]);
        float c = fv*c0[m][r] + iv*gv;
        c0[m][r] = c;
        hA[ca^1][sidx(m*16 + lgrp*4 + r, col)] = f2bf(ov*tanhf_(c));
      }
    }
    __syncthreads();
    // ---------- layer 1: [h0_new | h1] @ W^T ----------
    short8 w1f[4][8];
    #pragma unroll
    for (int g = 0; g < 4; ++g)
      #pragma unroll
      for (int kt = 0; kt < 8; ++kt)
        w1f[g][kt] = *(const short8*)&pw1[(g*8 + kt)*512];
    #pragma unroll
    for (int m = 0; m < 4; ++m){
      const int arow = m*16 + lidx;
      short8 a[8];
      #pragma unroll
      for (int kt = 0; kt < 4; ++kt)
        a[kt] = *(const short8*)&hA[ca^1][sidx(arow, kt*32 + lgrp*8)];
      #pragma unroll
      for (int kt = 0; kt < 4; ++kt)
        a[4+kt] = *(const short8*)&hB[cb][sidx(arow, kt*32 + lgrp*8)];
      f32x4 acc[4];
      #pragma unroll
      for (int g = 0; g < 4; ++g){
        f32x4 s = {0.f,0.f,0.f,0.f};
        #pragma unroll
        for (int kt = 0; kt < 8; ++kt)
          s = __builtin_amdgcn_mfma_f32_16x16x32_bf16(a[kt], w1f[g][kt], s, 0, 0, 0);
        acc[g] = s;
      }
      #pragma unroll
      for (int r = 0; r < 4; ++r){
        float iv = sigf(acc[0][r] + b1v[0]);
        float fv = sigf(acc[1][r] + b1v[1]);
        float gv = tanhf_(acc[2][r] + b1v[2]);
        float ov = sigf(acc[3][r] + b1v[3]);
        float c = fv*c1[m][r] + iv*gv;
        c1[m][r] = c;
        hB[cb^1][sidx(m*16 + lgrp*4 + r, col)] = f2bf(ov*tanhf_(c));
      }
    }
    __syncthreads();
    ca ^= 1; cb ^= 1;
  }

  // ===================== decoder =====================
  const unsigned short* pw2 = pk + SET2 + (w*4)*(8*512) + lane*8;
  short8 wdf[4][8];
  #pragma unroll
  for (int g = 0; g < 4; ++g)
    #pragma unroll
    for (int kt = 0; kt < 8; ++kt)
      wdf[g][kt] = *(const short8*)&pw2[(g*8 + kt)*512];
  short8 whf[4];
  {
    const short8 z8 = {0,0,0,0,0,0,0,0};
    #pragma unroll
    for (int kt = 0; kt < 4; ++kt) whf[kt] = z8;
    if (w < 4){
      #pragma unroll
      for (int kt = 0; kt < 4; ++kt)
        whf[kt] = *(const short8*)&pk[SET3 + kt*512 + lane*8];
    }
  }

  const float wpa = Wp[col*131 + 0], wpb = Wp[col*131 + 1], wpc = Wp[col*131 + 2];
  const float lngv = lng[col], lnbv = lnb[col];
  float bdv[4];
  #pragma unroll
  for (int g = 0; g < 4; ++g) bdv[g] = bdg[g*128 + col];
  float bmo = 0.f;
  if (lidx < 3) bmo = bm[lidx];
  else if (lidx < 6) bmo = bs[lidx - 3];

  if (tid < 192){
    int r = tid / 3, o = tid - r*3;
    u.d.prevb[r][o] = x[(size_t)(row0 + r)*90 + 14*6 + o];
  }
  __syncthreads();

  int cbd = 1;   // h1 lives in hB[1] after 15 toggles
  #pragma unroll 1
  for (int s = 0; s < 10; ++s){
    // ph1: dec_in = relu(dbase + prev @ Wp3^T) -> hA[0]
    const float dbs = dbase[s*128 + col];
    #pragma unroll
    for (int m = 0; m < 4; ++m)
      #pragma unroll
      for (int r = 0; r < 4; ++r){
        const int row = m*16 + lgrp*4 + r;
        f32x4 pv = *(const f32x4*)&u.d.prevb[row][0];
        float v = dbs + pv[0]*wpa + pv[1]*wpb + pv[2]*wpc;
        hA[0][sidx(row, col)] = f2bf(v > 0.f ? v : 0.f);
      }
    __syncthreads();

    // ph2: LSTM cell
    float hv[4][4];
    #pragma unroll
    for (int m = 0; m < 4; ++m){
      const int arow = m*16 + lidx;
      short8 a[8];
      #pragma unroll
      for (int kt = 0; kt < 4; ++kt)
        a[kt] = *(const short8*)&hA[0][sidx(arow, kt*32 + lgrp*8)];
      #pragma unroll
      for (int kt = 0; kt < 4; ++kt)
        a[4+kt] = *(const short8*)&hB[cbd][sidx(arow, kt*32 + lgrp*8)];
      f32x4 acc[4];
      #pragma unroll
      for (int g = 0; g < 4; ++g){
        f32x4 sa = {0.f,0.f,0.f,0.f};
        #pragma unroll
        for (int kt = 0; kt < 8; ++kt)
          sa = __builtin_amdgcn_mfma_f32_16x16x32_bf16(a[kt], wdf[g][kt], sa, 0, 0, 0);
        acc[g] = sa;
      }
      #pragma unroll
      for (int r = 0; r < 4; ++r){
        float iv = sigf(acc[0][r] + bdv[0]);
        float fv = sigf(acc[1][r] + bdv[1]);
        float gv = tanhf_(acc[2][r] + bdv[2]);
        float ov = sigf(acc[3][r] + bdv[3]);
        float c = fv*c1[m][r] + iv*gv;
        c1[m][r] = c;
        float h = ov*tanhf_(c);
        hv[m][r] = h;
        hB[cbd^1][sidx(m*16 + lgrp*4 + r, col)] = f2bf(h);
      }
    }
    // LN partials over this wave's 16 cols (reduce across lidx)
    {
      float s1[4][4];
      #pragma unroll
      for (int m = 0; m < 4; ++m)
        #pragma unroll
        for (int r = 0; r < 4; ++r) s1[m][r] = hv[m][r];
      #pragma unroll
      for (int d = 1; d < 16; d <<= 1)
        #pragma unroll
        for (int m = 0; m < 4; ++m)
          #pragma unroll
          for (int r = 0; r < 4; ++r) s1[m][r] += __shfl_xor(s1[m][r], d);
      if (lidx == 0){
        #pragma unroll
        for (int m = 0; m < 4; ++m)
          #pragma unroll
          for (int r = 0; r < 4; ++r)
            u.d.sred[w][m*16 + lgrp*4 + r][0] = s1[m][r];
      }
      float s2[4][4];
      #pragma unroll
      for (int m = 0; m < 4; ++m)
        #pragma unroll
        for (int r = 0; r < 4; ++r) s2[m][r] = hv[m][r]*hv[m][r];
      #pragma unroll
      for (int d = 1; d < 16; d <<= 1)
        #pragma unroll
        for (int m = 0; m < 4; ++m)
          #pragma unroll
          for (int r = 0; r < 4; ++r) s2[m][r] += __shfl_xor(s2[m][r], d);
      if (lidx == 0){
        #pragma unroll
        for (int m = 0; m < 4; ++m)
          #pragma unroll
          for (int r = 0; r < 4; ++r)
            u.d.sred[w][m*16 + lgrp*4 + r][1] = s2[m][r];
      }
    }
    __syncthreads();
    // ph3: finalize LN stats
    if (tid < 64){
      float ss = 0.f, sq = 0.f;
      #pragma unroll
      for (int ww = 0; ww < 8; ++ww){ ss += u.d.sred[ww][tid][0]; sq += u.d.sred[ww][tid][1]; }
      float mu = ss * (1.f/128.f);
      float var = sq * (1.f/128.f) - mu*mu;
      u.d.mus[tid][0] = mu;
      u.d.mus[tid][1] = __builtin_amdgcn_rsqf(var + 1e-5f);
    }
    __syncthreads();
    // ph4: feat -> hA[0] (overwrites dec_in)
    #pragma unroll
    for (int m = 0; m < 4; ++m)
      #pragma unroll
      for (int r = 0; r < 4; ++r){
        const int row = m*16 + lgrp*4 + r;
        float mu = u.d.mus[row][0], rs = u.d.mus[row][1];
        hA[0][sidx(row, col)] = f2bf((hv[m][r] - mu)*rs*lngv + lnbv);
      }
    __syncthreads();
    // ph5: heads via MFMA (waves 0..3, M-tile = wave)
    if (w < 4){
      const int arow = w*16 + lidx;
      short8 a[4];
      #pragma unroll
      for (int kt = 0; kt < 4; ++kt)
        a[kt] = *(const short8*)&hA[0][sidx(arow, kt*32 + lgrp*8)];
      f32x4 acc = {0.f,0.f,0.f,0.f};
      #pragma unroll
      for (int kt = 0; kt < 4; ++kt)
        acc = __builtin_amdgcn_mfma_f32_16x16x32_bf16(a[kt], whf[kt], acc, 0, 0, 0);
      #pragma unroll
      for (int r = 0; r < 4; ++r){
        const int row = w*16 + lgrp*4 + r;
        float v = acc[r] + bmo;
        if (lidx < 3){
          out[(size_t)(row0 + row)*30 + s*3 + lidx] = v;
          u.d.prevb[row][lidx] = v;
        } else if (lidx < 6){
          out[(size_t)65536*30 + (size_t)(row0 + row)*30 + s*3 + (lidx - 3)] =
              fminf(fmaxf(v, -6.f), 3.f);
        }
      }
    }
    __syncthreads();
    cbd ^= 1;
  }
}

extern "C" void kernel_launch(void* const* d_in, const int* in_sizes, int n_in,
                              void* d_out, int out_size, void* d_ws, size_t ws_size,
                              hipStream_t stream)
{
  const float* x    = (const float*)d_in[0];
  const float* Wih0 = (const float*)d_in[1];
  const float* Whh0 = (const float*)d_in[2];
  const float* b0   = (const float*)d_in[3];
  const float* Wih1 = (const float*)d_in[4];
  const float* Whh1 = (const float*)d_in[5];
  const float* b1   = (const float*)d_in[6];
  const float* Wihd = (const float*)d_in[7];
  const float* Whhd = (const float*)d_in[8];
  const float* bd   = (const float*)d_in[9];
  const float* emb  = (const float*)d_in[10];
  const float* Wp   = (const float*)d_in[11];
  const float* bp   = (const float*)d_in[12];
  const float* Wm   = (const float*)d_in[13];
  const float* bm   = (const float*)d_in[14];
  const float* Ws   = (const float*)d_in[15];
  const float* bs   = (const float*)d_in[16];
  const float* lng  = (const float*)d_in[17];
  const float* lnb  = (const float*)d_in[18];

  unsigned short* pkw = (unsigned short*)d_ws;
  float* dbase = (float*)((char*)d_ws + DBASE_OFF);

  pack_w<<<(PK_TOTAL + 255)/256, 256, 0, stream>>>(Wih0, Whh0, Wih1, Whh1,
                                                   Wihd, Whhd, Wm, Ws, pkw);
  prep_decbase<<<10, 128, 0, stream>>>(emb, Wp, bp, dbase);
  traj_main<<<1024, 512, 0, stream>>>(x, pkw, dbase, b0, b1, bd, Wp,
                                      bm, bs, lng, lnb, (float*)d_out);
}